// Round 10
// baseline (317.077 us; speedup 1.0000x reference)
//
#include <hip/hip_runtime.h>

#define L_LM 2000
#define F_DIM 64
#define B_SZ 2048

#define SPANS_PER_ROW 125          // 2000/16 landmarks
#define SPAN_F4 256                // 16*64/4 float4 per span
#define DGRID 250                  // 250 blocks x 256 thr = 1000 waves
#define DK 256                     // b-steps: 8 phases x 256 = 2048 rows

typedef float f32x4 __attribute__((ext_vector_type(4)));

// ---------------- Kernel 1: BMU (argmin of squared distance) ----------------
__global__ __launch_bounds__(256) void som_bmu_kernel(
    const float* __restrict__ x, const float* __restrict__ lm,
    int* __restrict__ min_idx)
{
    constexpr int ROWS = 8;
    const int b0 = blockIdx.x * ROWS;
    const int tid = threadIdx.x;

    __shared__ float xs[ROWS][F_DIM];
    for (int i = tid; i < ROWS * F_DIM; i += 256) {
        xs[i / F_DIM][i % F_DIM] = x[(size_t)(b0 + i / F_DIM) * F_DIM + (i % F_DIM)];
    }
    __syncthreads();

    float best[ROWS];
    int   bidx[ROWS];
#pragma unroll
    for (int r = 0; r < ROWS; ++r) { best[r] = 3.4e38f; bidx[r] = 0; }

    for (int l = tid; l < L_LM; l += 256) {
        const float4* lp = reinterpret_cast<const float4*>(lm + (size_t)l * F_DIM);
        float dot[ROWS];
        float l2 = 0.f;
#pragma unroll
        for (int r = 0; r < ROWS; ++r) dot[r] = 0.f;
#pragma unroll
        for (int k = 0; k < F_DIM / 4; ++k) {
            float4 v = lp[k];
            l2 += v.x * v.x + v.y * v.y + v.z * v.z + v.w * v.w;
#pragma unroll
            for (int r = 0; r < ROWS; ++r) {
                dot[r] += v.x * xs[r][4 * k + 0] + v.y * xs[r][4 * k + 1]
                        + v.z * xs[r][4 * k + 2] + v.w * xs[r][4 * k + 3];
            }
        }
#pragma unroll
        for (int r = 0; r < ROWS; ++r) {
            float s = l2 - 2.f * dot[r];
            if (s < best[r]) { best[r] = s; bidx[r] = l; }
        }
    }

#pragma unroll
    for (int r = 0; r < ROWS; ++r) {
        float s = best[r]; int i = bidx[r];
        for (int off = 32; off > 0; off >>= 1) {
            float s2 = __shfl_down(s, off);
            int   i2 = __shfl_down(i, off);
            if (s2 < s || (s2 == s && i2 < i)) { s = s2; i = i2; }
        }
        best[r] = s; bidx[r] = i;
    }

    __shared__ float sbest[4][ROWS];
    __shared__ int   sidx[4][ROWS];
    const int wave = tid >> 6;
    const int lane = tid & 63;
    if (lane == 0) {
#pragma unroll
        for (int r = 0; r < ROWS; ++r) { sbest[wave][r] = best[r]; sidx[wave][r] = bidx[r]; }
    }
    __syncthreads();
    if (tid < ROWS) {
        float s = sbest[0][tid]; int i = sidx[0][tid];
#pragma unroll
        for (int w = 1; w < 4; ++w) {
            float s2 = sbest[w][tid]; int i2 = sidx[w][tid];
            if (s2 < s || (s2 == s && i2 < i)) { s = s2; i = i2; }
        }
        min_idx[b0 + tid] = i;
    }
}

// ---------------- Kernel 1c: h precompute (hs[b][l] = qd[min_idx[b]][l]) ---
__global__ __launch_bounds__(256) void som_h_kernel(
    const float* __restrict__ qd, const int* __restrict__ min_idx,
    f32x4* __restrict__ hs4)
{
    constexpr unsigned NH4 = (unsigned)B_SZ * (L_LM / 4);
    constexpr unsigned RH4 = L_LM / 4;
    const f32x4* __restrict__ qd4 = reinterpret_cast<const f32x4*>(qd);
    const unsigned stride = gridDim.x * 256u;
    for (unsigned i = blockIdx.x * 256u + threadIdx.x; i < NH4; i += stride) {
        const unsigned b = i / RH4;
        const unsigned c = i - b * RH4;
        hs4[i] = qd4[(unsigned)min_idx[b] * RH4 + c];
    }
}

// ---------------- Kernel 2: delta0 — register-lm + PLAIN stores ------------
// Final untested cell vs the 6.87 TB/s fill: PLAIN (L2-allocating) stores in
// a compact sliding window with a near-zero-load loop. Transposed wave
// mapping: each wave FIXES its landmark span sr (lm fragment = 16
// loop-invariant VGPRs, loaded once) and iterates over batch rows b =
// b8 + 8k. At step k the 1000 waves cover b-rows [8k,8k+8) x all sr =
// one contiguous 4 MB window sliding through out (fill-like). Per 4 KB
// stored the loop loads only 4 h-dwords + 1 x-float4 (~80 B, prefetched
// 1-ahead so the vmcnt wait never drains stores). Plain stores let L2
// batch write-backs into address-sorted bursts — the fill's mechanism;
// nothing hot remains in L2 to pollute (lm is in registers).
__global__ __launch_bounds__(256) void som_delta_kernel(
    const float* __restrict__ x, const float* __restrict__ lm,
    const float* __restrict__ hs, f32x4* __restrict__ out)
{
    const int lane = threadIdx.x & 63;
    const int gw   = (blockIdx.x << 2) | (threadIdx.x >> 6);  // 0..999
    const unsigned sr = (unsigned)gw % (unsigned)SPANS_PER_ROW; // fixed span
    const unsigned b8 = (unsigned)gw / (unsigned)SPANS_PER_ROW; // 0..7
    const unsigned s4 = (unsigned)(lane >> 4);
    const unsigned f4 = (unsigned)(lane & 15);
    const f32x4* __restrict__ lm4 = reinterpret_cast<const f32x4*>(lm);
    const f32x4* __restrict__ x4  = reinterpret_cast<const f32x4*>(x);

    // lm span fragment: loop-invariant (16 VGPR), read once per wave
    const f32x4 L0 = lm4[sr * SPAN_F4 + lane];
    const f32x4 L1 = lm4[sr * SPAN_F4 + 64u + lane];
    const f32x4 L2 = lm4[sr * SPAN_F4 + 128u + lane];
    const f32x4 L3 = lm4[sr * SPAN_F4 + 192u + lane];

#define PF(BB, H0, H1, H2, H3, XV)                                        \
    {                                                                     \
        const float* hp_ = hs + (BB) * (unsigned)L_LM + sr * 16u + s4;    \
        H0 = hp_[0]; H1 = hp_[4]; H2 = hp_[8]; H3 = hp_[12];              \
        XV = x4[((BB) << 4) | f4];                                        \
    }

#define ST(BB, H0, H1, H2, H3, XV)                                        \
    {                                                                     \
        f32x4* ob_ = out + (size_t)(BB) * 32000u + sr * SPAN_F4 + lane;   \
        f32x4 o_;                                                         \
        o_.x = H0 * (XV.x - L0.x); o_.y = H0 * (XV.y - L0.y);             \
        o_.z = H0 * (XV.z - L0.z); o_.w = H0 * (XV.w - L0.w);             \
        ob_[0] = o_;                                                      \
        o_.x = H1 * (XV.x - L1.x); o_.y = H1 * (XV.y - L1.y);             \
        o_.z = H1 * (XV.z - L1.z); o_.w = H1 * (XV.w - L1.w);             \
        ob_[64] = o_;                                                     \
        o_.x = H2 * (XV.x - L2.x); o_.y = H2 * (XV.y - L2.y);             \
        o_.z = H2 * (XV.z - L2.z); o_.w = H2 * (XV.w - L2.w);             \
        ob_[128] = o_;                                                    \
        o_.x = H3 * (XV.x - L3.x); o_.y = H3 * (XV.y - L3.y);             \
        o_.z = H3 * (XV.z - L3.z); o_.w = H3 * (XV.w - L3.w);             \
        ob_[192] = o_;                                                    \
    }

    float ha0, ha1, ha2, ha3;  f32x4 xa;
    float hc0, hc1, hc2, hc3;  f32x4 xc;

    unsigned b = b8;
    PF(b, ha0, ha1, ha2, ha3, xa);

    for (int k = 0; k < DK; k += 2) {
        const unsigned b1 = b + 8u;                         // k+1 row (valid: <=2047)
        const unsigned b2 = (k + 2 < DK) ? b1 + 8u : b1;    // clamp final prefetch
        PF(b1, hc0, hc1, hc2, hc3, xc);
        ST(b,  ha0, ha1, ha2, ha3, xa);
        PF(b2, ha0, ha1, ha2, ha3, xa);
        ST(b1, hc0, hc1, hc2, hc3, xc);
        b = b2;
    }
#undef PF
#undef ST
}

extern "C" void kernel_launch(void* const* d_in, const int* in_sizes, int n_in,
                              void* d_out, int out_size, void* d_ws, size_t ws_size,
                              hipStream_t stream) {
    const float* x  = (const float*)d_in[0];
    const float* lm = (const float*)d_in[1];
    const float* qd = (const float*)d_in[2];
    float* out = (float*)d_out;

    int*   midx = (int*)d_ws;
    float* hs   = (float*)((char*)d_ws + (1u << 20));

    som_bmu_kernel<<<B_SZ / 8, 256, 0, stream>>>(x, lm, midx);
    som_h_kernel<<<1024, 256, 0, stream>>>(qd, midx, (f32x4*)hs);
    som_delta_kernel<<<DGRID, 256, 0, stream>>>(x, lm, hs, (f32x4*)out);
}